// Round 19
// baseline (665.447 us; speedup 1.0000x reference)
//
#include <hip/hip_runtime.h>
#include <cfloat>

#define NRW 32768
#define KC 4096
#define CD 256
#define HW 1024
#define CAP 64
#define WIN 1e-3f

typedef short bf16x8 __attribute__((ext_vector_type(8)));
typedef float f32x4 __attribute__((ext_vector_type(4)));

__device__ __forceinline__ unsigned short f2bf(float f) {  // RNE f32->bf16
  unsigned int u = __float_as_uint(f);
  u = (u + 0x7FFFu + ((u >> 16) & 1u)) >> 16;
  return (unsigned short)u;
}

// min across each 16-lane DPP row, pure VALU [verified r16-r18]
__device__ __forceinline__ float dppmin16(float v) {
  float t;
  t = __uint_as_float(__builtin_amdgcn_update_dpp(0, __float_as_uint(v), 0xB1, 0xF, 0xF, true));
  v = fminf(v, t);
  t = __uint_as_float(__builtin_amdgcn_update_dpp(0, __float_as_uint(v), 0x4E, 0xF, 0xF, true));
  v = fminf(v, t);
  t = __uint_as_float(__builtin_amdgcn_update_dpp(0, __float_as_uint(v), 0x141, 0xF, 0xF, true));
  v = fminf(v, t);
  t = __uint_as_float(__builtin_amdgcn_update_dpp(0, __float_as_uint(v), 0x140, 0xF, 0xF, true));
  v = fminf(v, t);
  return v;
}

// ---------- se[k] = np.sum(cb[k]**2) : numpy pairwise [verified] ----------
__global__ __launch_bounds__(256) void vq_se(const float* __restrict__ cb,
                                             float* __restrict__ se) {
#pragma clang fp contract(off)
  const int tid = threadIdx.x;
  const int g = tid >> 3;
  const int j = tid & 7;
  const int code = blockIdx.x * 32 + g;
  const float* e = cb + (size_t)code * CD;
  float half[2];
#pragma unroll
  for (int h = 0; h < 2; ++h) {
    const float* a = e + h * 128;
    float v = a[j];
    float r = v * v;
#pragma unroll
    for (int i = 1; i < 16; ++i) {
      float w = a[8 * i + j];
      float w2 = w * w;
      r = r + w2;
    }
    float l1 = r + __shfl_down(r, 1, 8);
    float l2 = l1 + __shfl_down(l1, 2, 8);
    float l3 = l2 + __shfl_down(l2, 4, 8);
    half[h] = l3;
  }
  if (j == 0) se[code] = half[0] + half[1];
}

// ---------- convert x -> xh[row][ch] bf16 (transpose, RNE) [verified] ----------
__global__ __launch_bounds__(256) void vq_cvt_x(const float* __restrict__ x,
                                                unsigned short* __restrict__ xh) {
  const int t = threadIdx.x;                  // channel
  const int b = blockIdx.x >> 4;
  const int hw0 = (blockIdx.x & 15) << 6;
  const float* src = x + ((size_t)b * CD + t) * HW + hw0;
  unsigned short* dst = xh + ((size_t)b * HW + hw0) * CD + t;
#pragma unroll
  for (int f = 0; f < 16; ++f) {
    const float4 v = *(const float4*)(src + 4 * f);
    dst[(size_t)(4 * f + 0) * CD] = f2bf(v.x);
    dst[(size_t)(4 * f + 1) * CD] = f2bf(v.y);
    dst[(size_t)(4 * f + 2) * CD] = f2bf(v.z);
    dst[(size_t)(4 * f + 3) * CD] = f2bf(v.w);
  }
}

// ---------- convert cb -> eh in B-FRAGMENT order ----------
// granule gid = QG*512 + kb*64 + lane, lane = lq*16 + ll:
//   holds code QG*16 + ll, channels [(kb*4+lq)*8, +8)
// so a wave's 8 loads per chunk (one per kb) are 64x16B contiguous = coalesced.
__global__ __launch_bounds__(256) void vq_cvt_e(const float* __restrict__ cb,
                                                unsigned short* __restrict__ eh) {
  const int gid = blockIdx.x * 256 + threadIdx.x;   // 131072 granules
  const int QG = gid >> 9;
  const int kb = (gid >> 6) & 7;
  const int lane = gid & 63;
  const int lq = lane >> 4, ll = lane & 15;
  const int code = (QG << 4) | ll;
  const int c8 = kb * 4 + lq;
  const float* s = cb + (size_t)code * CD + (c8 << 3);
  uint4 v;
  v.x = (unsigned)f2bf(s[0]) | ((unsigned)f2bf(s[1]) << 16);
  v.y = (unsigned)f2bf(s[2]) | ((unsigned)f2bf(s[3]) << 16);
  v.z = (unsigned)f2bf(s[4]) | ((unsigned)f2bf(s[5]) << 16);
  v.w = (unsigned)f2bf(s[6]) | ((unsigned)f2bf(s[7]) << 16);
  *(uint4*)(eh + (size_t)gid * 8) = v;
}

// ---------- zero cnt + nflg ----------
__global__ __launch_bounds__(256) void vq_init(int* __restrict__ cnt,
                                               int* __restrict__ nflg) {
  const int i = blockIdx.x * 256 + threadIdx.x;
  cnt[i] = 0;
  if (i == 0) *nflg = 0;
}

// one pipeline step: prefetch chunk Q+1 into NXT regs, compute chunk Q from CUR
#define STEP(CUR, NXT, Q)                                                           \
  {                                                                                 \
    if ((Q) < 63) {                                                                 \
      const unsigned short* gb = ehw + ((size_t)((Q) + 1) * 512 + l) * 8;           \
      _Pragma("unroll")                                                             \
      for (int kb = 0; kb < 8; ++kb) NXT[kb] = *(const bf16x8*)(gb + kb * 512);     \
      sev_nxt = se[kwbase + ((Q) + 1) * 16 + ll];                                   \
    }                                                                               \
    f32x4 acc0 = (f32x4){0.f, 0.f, 0.f, 0.f};                                       \
    f32x4 acc1 = (f32x4){0.f, 0.f, 0.f, 0.f};                                       \
    _Pragma("unroll")                                                               \
    for (int kb = 0; kb < 8; ++kb) {                                                \
      acc0 = __builtin_amdgcn_mfma_f32_16x16x32_bf16(afr[0][kb], CUR[kb], acc0, 0, 0, 0); \
      acc1 = __builtin_amdgcn_mfma_f32_16x16x32_bf16(afr[1][kb], CUR[kb], acc1, 0, 0, 0); \
    }                                                                               \
    const float sev = sev_cur;                                                      \
    float sv[2][4];                                                                 \
    _Pragma("unroll")                                                               \
    for (int r = 0; r < 4; ++r) {                                                   \
      sv[0][r] = sev - 2.0f * acc0[r];                                              \
      if (sv[0][r] < run[0][r]) run[0][r] = sv[0][r];                               \
      sv[1][r] = sev - 2.0f * acc1[r];                                              \
      if (sv[1][r] < run[1][r]) run[1][r] = sv[1][r];                               \
    }                                                                               \
    float rr[2][4];                                                                 \
    _Pragma("unroll")                                                               \
    for (int mt = 0; mt < 2; ++mt)                                                  \
      _Pragma("unroll")                                                             \
      for (int r = 0; r < 4; ++r) rr[mt][r] = dppmin16(run[mt][r]) + WIN;           \
    _Pragma("unroll")                                                               \
    for (int mt = 0; mt < 2; ++mt)                                                  \
      _Pragma("unroll")                                                             \
      for (int r = 0; r < 4; ++r) {                                                 \
        if (sv[mt][r] <= rr[mt][r]) {                                               \
          const int row = rowbase + mt * 16 + (lq << 2) + r;                        \
          const int code = kwbase + (Q) * 16 + ll;                                  \
          const int pos = atomicAdd(&cnt[row], 1);                                  \
          if (pos < CAP) cand[(size_t)row * CAP + pos] = code;                      \
        }                                                                           \
      }                                                                             \
    sev_cur = sev_nxt;                                                              \
  }

// ---------- MFMA filter GEMM: no LDS, no barriers, wave-private reg pipeline ----------
// block = 32 rows; wave w owns codes [1024w, +1024) in 16-code chunks.
__global__ __launch_bounds__(256, 2) void vq_gemm(const unsigned short* __restrict__ xh,
                                                  const unsigned short* __restrict__ eh,
                                                  const float* __restrict__ se,
                                                  int* __restrict__ cnt,
                                                  int* __restrict__ cand) {
  const int t = threadIdx.x;
  const int l = t & 63;
  const int w = t >> 6;
  const int rowbase = blockIdx.x * 32;
  const int lq = l >> 4;
  const int ll = l & 15;
  const int kwbase = w << 10;                 // wave's 1024-code range
  const unsigned short* ehw = eh + (size_t)w * 262144;  // 64 chunks x 4096 shorts

  // A fragments: 2 m-tiles x 8 kb (resident, 64 VGPR); lane = (row ll, k-slice lq)
  bf16x8 afr[2][8];
#pragma unroll
  for (int mt = 0; mt < 2; ++mt) {
    const unsigned short* ga = xh + (size_t)(rowbase + mt * 16 + ll) * CD + (lq << 3);
#pragma unroll
    for (int kb = 0; kb < 8; ++kb)
      afr[mt][kb] = *(const bf16x8*)(ga + (kb << 5));
  }

  float run[2][4];
#pragma unroll
  for (int mt = 0; mt < 2; ++mt)
#pragma unroll
    for (int r = 0; r < 4; ++r) run[mt][r] = FLT_MAX;

  // prologue: chunk 0 -> bfrA, se chunk 0
  bf16x8 bfrA[8], bfrB[8];
  {
    const unsigned short* gb = ehw + (size_t)l * 8;
#pragma unroll
    for (int kb = 0; kb < 8; ++kb) bfrA[kb] = *(const bf16x8*)(gb + kb * 512);
  }
  float sev_cur = se[kwbase + ll];
  float sev_nxt;

#pragma unroll 1
  for (int cp = 0; cp < 32; ++cp) {
    STEP(bfrA, bfrB, 2 * cp);
    STEP(bfrB, bfrA, 2 * cp + 1);
  }
}

// ---------- np-exact recheck of candidates (8 rows/block, 32 lanes/row) [verified] ----------
__global__ __launch_bounds__(256) void vq_recheck(const float* __restrict__ x,
                                                  const float* __restrict__ cb,
                                                  const float* __restrict__ se,
                                                  const int* __restrict__ cnt,
                                                  const int* __restrict__ cand,
                                                  float* __restrict__ outids,
                                                  int* __restrict__ flg,
                                                  int* __restrict__ nflg) {
#pragma clang fp contract(off)
  __shared__ float xr[8][256];
  __shared__ float sxs[8];
  const int t = threadIdx.x;
  const int r0 = blockIdx.x * 8;
  const int b = r0 >> 10, hw0 = r0 & 1023;
  {
    const float* px = x + ((size_t)b * CD + t) * HW + hw0;
    const float4 v0 = *(const float4*)(px);
    const float4 v1 = *(const float4*)(px + 4);
    xr[0][t] = v0.x; xr[1][t] = v0.y; xr[2][t] = v0.z; xr[3][t] = v0.w;
    xr[4][t] = v1.x; xr[5][t] = v1.y; xr[6][t] = v1.z; xr[7][t] = v1.w;
  }
  __syncthreads();
  if (t < 8) {   // np pairwise sx (verified order)
    float half[2];
#pragma unroll
    for (int h = 0; h < 2; ++h) {
      float racc[8];
#pragma unroll
      for (int j = 0; j < 8; ++j) { const float v = xr[t][h * 128 + j]; racc[j] = v * v; }
#pragma unroll
      for (int i = 1; i < 16; ++i)
#pragma unroll
        for (int j = 0; j < 8; ++j) {
          const float v = xr[t][h * 128 + 8 * i + j];
          const float v2 = v * v;
          racc[j] = racc[j] + v2;
        }
      half[h] = ((racc[0] + racc[1]) + (racc[2] + racc[3])) +
                ((racc[4] + racc[5]) + (racc[6] + racc[7]));
    }
    sxs[t] = half[0] + half[1];
  }
  __syncthreads();

  const int g = t >> 5, ln = t & 31;
  const int row = r0 + g;
  const int cn = cnt[row];
  float bv = FLT_MAX;
  int bi = 0x7FFFFFFF;
  if (cn > CAP) {
    if (ln == 0) { const int p = atomicAdd(nflg, 1); flg[p] = row; }
  } else {
    const float sx = sxs[g];
    const float* xrow = xr[g];
    for (int c = ln; c < cn; c += 32) {
      const int k = cand[(size_t)row * CAP + c];
      const float* ek = cb + (size_t)k * CD;
      float a0 = 0.f, a1 = 0.f, a2 = 0.f, a3 = 0.f;
      for (int B = 0; B < 16; ++B)
        for (int j = 3; j >= 0; --j) {
          const int c0 = 16 * B + 4 * j;
          float p0 = xrow[c0 + 0] * ek[c0 + 0]; a0 = a0 + p0;
          float p1 = xrow[c0 + 1] * ek[c0 + 1]; a1 = a1 + p1;
          float p2 = xrow[c0 + 2] * ek[c0 + 2]; a2 = a2 + p2;
          float p3 = xrow[c0 + 3] * ek[c0 + 3]; a3 = a3 + p3;
        }
      const float dot = (a0 + a1) + (a2 + a3);
      const float dist = (se[k] + sx) - 2.0f * dot;
      if (dist < bv || (dist == bv && k < bi)) { bv = dist; bi = k; }
    }
  }
#pragma unroll
  for (int off = 1; off < 32; off <<= 1) {
    const float ov = __shfl_xor(bv, off, 32);
    const int oi = __shfl_xor(bi, off, 32);
    if (ov < bv || (ov == bv && oi < bi)) { bv = ov; bi = oi; }
  }
  if (ln == 0 && cn <= CAP) outids[row] = (float)bi;
}

// ---------- full-row np-exact fallback for overflow rows [verified] ----------
__global__ __launch_bounds__(256) void vq_fallback(const float* __restrict__ x,
                                                   const float* __restrict__ cb,
                                                   const float* __restrict__ se,
                                                   const int* __restrict__ flg,
                                                   const int* __restrict__ nflg,
                                                   float* __restrict__ outids) {
#pragma clang fp contract(off)
  __shared__ float xr[256];
  __shared__ float sxv;
  __shared__ float rv[256];
  __shared__ int ri[256];
  const int t = threadIdx.x;
  const int nf = *nflg;
  for (int fi = blockIdx.x; fi < nf; fi += gridDim.x) {
    const int row = flg[fi];
    const int b = row >> 10, hw = row & 1023;
    __syncthreads();
    xr[t] = x[((size_t)b * CD + t) * HW + hw];
    __syncthreads();
    if (t == 0) {
      float half[2];
      for (int h = 0; h < 2; ++h) {
        float racc[8];
        for (int j = 0; j < 8; ++j) { const float v = xr[h * 128 + j]; racc[j] = v * v; }
        for (int i = 1; i < 16; ++i)
          for (int j = 0; j < 8; ++j) {
            const float v = xr[h * 128 + 8 * i + j];
            const float v2 = v * v;
            racc[j] = racc[j] + v2;
          }
        half[h] = ((racc[0] + racc[1]) + (racc[2] + racc[3])) +
                  ((racc[4] + racc[5]) + (racc[6] + racc[7]));
      }
      sxv = half[0] + half[1];
    }
    __syncthreads();
    float bv = FLT_MAX;
    int bi = 0x7FFFFFFF;
    for (int j = 0; j < 16; ++j) {
      const int k = j * 256 + t;
      const float* ek = cb + (size_t)k * CD;
      float a0 = 0.f, a1 = 0.f, a2 = 0.f, a3 = 0.f;
      for (int B = 0; B < 16; ++B)
        for (int jj = 3; jj >= 0; --jj) {
          const int c0 = 16 * B + 4 * jj;
          float p0 = xr[c0 + 0] * ek[c0 + 0]; a0 = a0 + p0;
          float p1 = xr[c0 + 1] * ek[c0 + 1]; a1 = a1 + p1;
          float p2 = xr[c0 + 2] * ek[c0 + 2]; a2 = a2 + p2;
          float p3 = xr[c0 + 3] * ek[c0 + 3]; a3 = a3 + p3;
        }
      const float dot = (a0 + a1) + (a2 + a3);
      const float dist = (se[k] + sxv) - 2.0f * dot;
      if (dist < bv || (dist == bv && k < bi)) { bv = dist; bi = k; }
    }
    rv[t] = bv; ri[t] = bi;
    __syncthreads();
    for (int off = 128; off > 0; off >>= 1) {
      if (t < off) {
        if (rv[t + off] < rv[t] || (rv[t + off] == rv[t] && ri[t + off] < ri[t])) {
          rv[t] = rv[t + off]; ri[t] = ri[t + off];
        }
      }
      __syncthreads();
    }
    if (t == 0) outids[row] = (float)ri[0];
  }
}

// ---------- emb gather [verified] ----------
__global__ __launch_bounds__(256) void vq_emb_out(const float* __restrict__ outids,
                                                  const float* __restrict__ cb,
                                                  float* __restrict__ out) {
  const int bx = blockIdx.x;
  const int b = bx >> 10;
  const int rem = bx & 1023;
  const int c = rem >> 2;
  const int q = rem & 3;
  const int hw = q * 256 + threadIdx.x;
  const int id = (int)outids[b * HW + hw];
  out[((size_t)(b * CD + c)) * HW + hw] = cb[(size_t)id * CD + c];
}

extern "C" void kernel_launch(void* const* d_in, const int* in_sizes, int n_in,
                              void* d_out, int out_size, void* d_ws, size_t ws_size,
                              hipStream_t stream) {
  const float* x  = (const float*)d_in[0];   // (32,256,32,32) f32
  const float* cb = (const float*)d_in[1];   // (4096,256) f32
  float* out = (float*)d_out;                // [0..32767]=ids, [32768..]=emb

  float* se = (float*)d_ws;                  // 16 KB

  // scratch inside the emb region (8,388,608 floats), overwritten last by gather
  float* sc = out + NRW;
  unsigned short* xh = (unsigned short*)sc;              // 16.8 MB
  unsigned short* eh = (unsigned short*)(sc + 4194304);  // 2.1 MB (fragment-ordered)
  int*   cnt  = (int*)(sc + 4751360);                    // 32,768
  int*   flg  = (int*)(sc + 4784128);                    // 32,768
  int*   nflg = (int*)(sc + 4816896);                    // 1
  int*   cand = (int*)(sc + 4816960);                    // 32768*64 ints

  vq_se<<<KC / 32, 256, 0, stream>>>(cb, se);
  vq_cvt_x<<<512, 256, 0, stream>>>(x, xh);
  vq_cvt_e<<<512, 256, 0, stream>>>(cb, eh);
  vq_init<<<128, 256, 0, stream>>>(cnt, nflg);
  vq_gemm<<<NRW / 32, 256, 0, stream>>>(xh, eh, se, cnt, cand);
  vq_recheck<<<NRW / 8, 256, 0, stream>>>(x, cb, se, cnt, cand, out, flg, nflg);
  vq_fallback<<<512, 256, 0, stream>>>(x, cb, se, flg, nflg, out);
  vq_emb_out<<<32768, 256, 0, stream>>>(out, cb, out + NRW);
}

// Round 21
// 478.326 us; speedup vs baseline: 1.3912x; 1.3912x over previous
//
#include <hip/hip_runtime.h>
#include <cfloat>

#define NRW 32768
#define KC 4096
#define CD 256
#define HW 1024
#define CAP 64
#define WIN 1e-3f
#define XPAD 258

typedef short bf16x8 __attribute__((ext_vector_type(8)));
typedef float f32x4 __attribute__((ext_vector_type(4)));

__device__ __forceinline__ unsigned short f2bf(float f) {  // RNE f32->bf16
  unsigned int u = __float_as_uint(f);
  u = (u + 0x7FFFu + ((u >> 16) & 1u)) >> 16;
  return (unsigned short)u;
}

// direct global->LDS 16B async copy [verified r17/r18]
__device__ __forceinline__ void gl2lds16(const unsigned short* g, unsigned short* l) {
  __builtin_amdgcn_global_load_lds(
      (const __attribute__((address_space(1))) void*)(const void*)g,
      (__attribute__((address_space(3))) void*)(void*)l, 16, 0, 0);
}

// min across each 16-lane DPP row, pure VALU [verified r16-r18]
__device__ __forceinline__ float dppmin16(float v) {
  float t;
  t = __uint_as_float(__builtin_amdgcn_update_dpp(0, __float_as_uint(v), 0xB1, 0xF, 0xF, true));
  v = fminf(v, t);
  t = __uint_as_float(__builtin_amdgcn_update_dpp(0, __float_as_uint(v), 0x4E, 0xF, 0xF, true));
  v = fminf(v, t);
  t = __uint_as_float(__builtin_amdgcn_update_dpp(0, __float_as_uint(v), 0x141, 0xF, 0xF, true));
  v = fminf(v, t);
  t = __uint_as_float(__builtin_amdgcn_update_dpp(0, __float_as_uint(v), 0x140, 0xF, 0xF, true));
  v = fminf(v, t);
  return v;
}

// ---------- se[k] = np.sum(cb[k]**2) : numpy pairwise [verified]; also zeroes nflg ----------
__global__ __launch_bounds__(256) void vq_se(const float* __restrict__ cb,
                                             float* __restrict__ se,
                                             int* __restrict__ nflg) {
#pragma clang fp contract(off)
  const int tid = threadIdx.x;
  if (blockIdx.x == 0 && tid == 0) *nflg = 0;
  const int g = tid >> 3;
  const int j = tid & 7;
  const int code = blockIdx.x * 32 + g;
  const float* e = cb + (size_t)code * CD;
  float half[2];
#pragma unroll
  for (int h = 0; h < 2; ++h) {
    const float* a = e + h * 128;
    float v = a[j];
    float r = v * v;
#pragma unroll
    for (int i = 1; i < 16; ++i) {
      float w = a[8 * i + j];
      float w2 = w * w;
      r = r + w2;
    }
    float l1 = r + __shfl_down(r, 1, 8);
    float l2 = l1 + __shfl_down(l1, 2, 8);
    float l3 = l2 + __shfl_down(l2, 4, 8);
    half[h] = l3;
  }
  if (j == 0) se[code] = half[0] + half[1];
}

// ---------- convert x -> xh[row][ch] bf16 (transpose, RNE) [verified] ----------
__global__ __launch_bounds__(256) void vq_cvt_x(const float* __restrict__ x,
                                                unsigned short* __restrict__ xh) {
  const int t = threadIdx.x;                  // channel
  const int b = blockIdx.x >> 4;
  const int hw0 = (blockIdx.x & 15) << 6;
  const float* src = x + ((size_t)b * CD + t) * HW + hw0;
  unsigned short* dst = xh + ((size_t)b * HW + hw0) * CD + t;
#pragma unroll
  for (int f = 0; f < 16; ++f) {
    const float4 v = *(const float4*)(src + 4 * f);
    dst[(size_t)(4 * f + 0) * CD] = f2bf(v.x);
    dst[(size_t)(4 * f + 1) * CD] = f2bf(v.y);
    dst[(size_t)(4 * f + 2) * CD] = f2bf(v.z);
    dst[(size_t)(4 * f + 3) * CD] = f2bf(v.w);
  }
}

// ---------- convert cb -> eh PRE-SWIZZLED granule layout (32-code chunks) [verified r18] ----------
__global__ __launch_bounds__(256) void vq_cvt_e(const float* __restrict__ cb,
                                                unsigned short* __restrict__ eh) {
  const int gid = blockIdx.x * 256 + threadIdx.x;   // 131072 granules
  const int cg = gid >> 10;
  const int c8 = (gid >> 5) & 31;
  const int m  = gid & 31;
  const int code = (cg << 5) | (m ^ (c8 & 7));
  const float* s = cb + (size_t)code * CD + (c8 << 3);
  uint4 v;
  v.x = (unsigned)f2bf(s[0]) | ((unsigned)f2bf(s[1]) << 16);
  v.y = (unsigned)f2bf(s[2]) | ((unsigned)f2bf(s[3]) << 16);
  v.z = (unsigned)f2bf(s[4]) | ((unsigned)f2bf(s[5]) << 16);
  v.w = (unsigned)f2bf(s[6]) | ((unsigned)f2bf(s[7]) << 16);
  *(uint4*)(eh + (size_t)gid * 8) = v;
}

// ---------- fused: r18 MFMA filter GEMM + LDS candidates + in-kernel np-exact recheck ----------
__global__ __launch_bounds__(256, 3) void vq_gemm_fused(const unsigned short* __restrict__ xh,
                                                        const unsigned short* __restrict__ eh,
                                                        const float* __restrict__ se,
                                                        const float* __restrict__ x,
                                                        const float* __restrict__ cb,
                                                        float* __restrict__ outids,
                                                        int* __restrict__ flg,
                                                        int* __restrict__ nflg) {
#pragma clang fp contract(off)
  __shared__ __align__(16) char smem[41472];
  unsigned short* esb = (unsigned short*)smem;          // main: es[2][8192 shorts] (32 KB)
  float* xr    = (float*)smem;                          // tail overlay: [32][XPAD] f32 (33 KB)
  int*   candl = (int*)(smem + 33024);                  // [32][CAP] (8 KB)
  int*   cntl  = (int*)(smem + 41216);                  // [32]
  float* sxs   = (float*)(smem + 41344);                // [32]

  const int t = threadIdx.x;
  const int l = t & 63;
  const int w = t >> 6;
  const int rs = (w & 1) * 16;            // row-slab base (16 rows)
  const int ch16 = (w >> 1) * 16;         // code half within 32-code chunk
  const int rowbase = blockIdx.x * 32;
  const int lq = l >> 4;
  const int ll = l & 15;

  if (t < 32) cntl[t] = 0;

  // A fragments: 8 kb for this wave's 16 rows (resident, 32 VGPR)
  bf16x8 afr[8];
  {
    const unsigned short* ga = xh + (size_t)(rowbase + rs + ll) * CD + (lq << 3);
#pragma unroll
    for (int kb = 0; kb < 8; ++kb)
      afr[kb] = *(const bf16x8*)(ga + (kb << 5));
  }

  float run[4], rr[4];
#pragma unroll
  for (int r = 0; r < 4; ++r) { run[r] = FLT_MAX; rr[r] = FLT_MAX; }

  // prologue: stage chunk 0 (wave w covers c8 in [8w,8w+8))
#pragma unroll
  for (int i = 0; i < 4; ++i) {
    const int gidx = (8 * w + 2 * i) * 32;
    gl2lds16(eh + ((size_t)gidx + l) * 8, esb + (size_t)gidx * 8);
  }
  __syncthreads();

#pragma unroll 1
  for (int cg = 0; cg < 128; ++cg) {
    if (cg < 127) {
      const size_t cb0 = (size_t)(cg + 1) * 1024;
      unsigned short* db = esb + ((cg + 1) & 1) * 8192;
#pragma unroll
      for (int i = 0; i < 4; ++i) {
        const int gidx = (8 * w + 2 * i) * 32;
        gl2lds16(eh + (cb0 + gidx + l) * 8, db + (size_t)gidx * 8);
      }
    }

    // compute chunk cg: 8 MFMA
    f32x4 acc = (f32x4){0.f, 0.f, 0.f, 0.f};
    const unsigned short* eb = esb + (cg & 1) * 8192;
#pragma unroll
    for (int kb = 0; kb < 8; ++kb) {
      const int c8 = (kb << 2) + lq;
      const int col = ch16 + ll;
      const bf16x8 bfr = *(const bf16x8*)&eb[((c8 << 5) + (col ^ (c8 & 7))) * 8];
      acc = __builtin_amdgcn_mfma_f32_16x16x32_bf16(afr[kb], bfr, acc, 0, 0, 0);
    }

    // epilogue: s' = se - 2*dot; running min; tighten every 2nd cg; collect to LDS
    const float sev = se[(cg << 5) + ch16 + ll];
    float sv[4];
#pragma unroll
    for (int r = 0; r < 4; ++r) {
      sv[r] = sev - 2.0f * acc[r];
      if (sv[r] < run[r]) run[r] = sv[r];
    }
    if ((cg & 1) == 0) {
#pragma unroll
      for (int r = 0; r < 4; ++r) rr[r] = dppmin16(run[r]) + WIN;
    }
#pragma unroll
    for (int r = 0; r < 4; ++r) {
      if (sv[r] <= rr[r]) {
        const int rowloc = rs + (lq << 2) + r;
        const int code = (cg << 5) + ch16 + ll;
        const int pos = atomicAdd(&cntl[rowloc], 1);
        if (pos < CAP) candl[rowloc * CAP + pos] = code;
      }
    }
    __syncthreads();
  }

  // ===== fused tail: np-exact recheck of this block's 32 rows (es is dead -> xr overlay) =====
  const int b = rowbase >> 10, hw0 = rowbase & 1023;
  {
    const float* px = x + ((size_t)b * CD + t) * HW + hw0;   // 32 floats, row-major in hw
#pragma unroll
    for (int f = 0; f < 8; ++f) {
      const float4 v = *(const float4*)(px + 4 * f);
      xr[(4 * f + 0) * XPAD + t] = v.x;
      xr[(4 * f + 1) * XPAD + t] = v.y;
      xr[(4 * f + 2) * XPAD + t] = v.z;
      xr[(4 * f + 3) * XPAD + t] = v.w;
    }
  }
  __syncthreads();

  // sx per row: numpy pairwise (128+128, 8-lane group tree) [verified pattern]
  {
    const int g = t >> 3, j = t & 7;
    float half[2];
#pragma unroll
    for (int h = 0; h < 2; ++h) {
      const float* a = xr + g * XPAD + h * 128;
      float v = a[j];
      float r = v * v;
#pragma unroll
      for (int i = 1; i < 16; ++i) {
        float ww = a[8 * i + j];
        float w2 = ww * ww;
        r = r + w2;
      }
      float l1 = r + __shfl_down(r, 1, 8);
      float l2 = l1 + __shfl_down(l1, 2, 8);
      float l3 = l2 + __shfl_down(l2, 4, 8);
      half[h] = l3;
    }
    if (j == 0) sxs[g] = half[0] + half[1];
  }
  __syncthreads();

  // recheck: 8 lanes per row; np-exact dist [verified inner routine]; lex first-min
  {
    const int g = t >> 3, j = t & 7;
    const int row = rowbase + g;
    const int cn = cntl[g];
    float bv = FLT_MAX;
    int bi = 0x7FFFFFFF;
    if (cn > CAP) {
      if (j == 0) { const int p = atomicAdd(nflg, 1); flg[p] = row; }
    } else {
      const float sx = sxs[g];
      const float* xrow = xr + g * XPAD;
      for (int c = j; c < cn; c += 8) {
        const int k = candl[g * CAP + c];
        const float* ek = cb + (size_t)k * CD;
        float a0 = 0.f, a1 = 0.f, a2 = 0.f, a3 = 0.f;
        for (int B = 0; B < 16; ++B)
          for (int jj = 3; jj >= 0; --jj) {
            const int c0 = 16 * B + 4 * jj;
            float p0 = xrow[c0 + 0] * ek[c0 + 0]; a0 = a0 + p0;
            float p1 = xrow[c0 + 1] * ek[c0 + 1]; a1 = a1 + p1;
            float p2 = xrow[c0 + 2] * ek[c0 + 2]; a2 = a2 + p2;
            float p3 = xrow[c0 + 3] * ek[c0 + 3]; a3 = a3 + p3;
          }
        const float dot = (a0 + a1) + (a2 + a3);
        const float dist = (se[k] + sx) - 2.0f * dot;
        if (dist < bv || (dist == bv && k < bi)) { bv = dist; bi = k; }
      }
#pragma unroll
      for (int off = 1; off < 8; off <<= 1) {
        const float ov = __shfl_xor(bv, off, 8);
        const int oi = __shfl_xor(bi, off, 8);
        if (ov < bv || (ov == bv && oi < bi)) { bv = ov; bi = oi; }
      }
      if (j == 0) outids[row] = (float)bi;
    }
  }
}

// ---------- full-row np-exact fallback for overflow rows [verified] ----------
__global__ __launch_bounds__(256) void vq_fallback(const float* __restrict__ x,
                                                   const float* __restrict__ cb,
                                                   const float* __restrict__ se,
                                                   const int* __restrict__ flg,
                                                   const int* __restrict__ nflg,
                                                   float* __restrict__ outids) {
#pragma clang fp contract(off)
  __shared__ float xr[256];
  __shared__ float sxv;
  __shared__ float rv[256];
  __shared__ int ri[256];
  const int t = threadIdx.x;
  const int nf = *nflg;
  for (int fi = blockIdx.x; fi < nf; fi += gridDim.x) {
    const int row = flg[fi];
    const int b = row >> 10, hw = row & 1023;
    __syncthreads();
    xr[t] = x[((size_t)b * CD + t) * HW + hw];
    __syncthreads();
    if (t == 0) {
      float half[2];
      for (int h = 0; h < 2; ++h) {
        float racc[8];
        for (int j = 0; j < 8; ++j) { const float v = xr[h * 128 + j]; racc[j] = v * v; }
        for (int i = 1; i < 16; ++i)
          for (int j = 0; j < 8; ++j) {
            const float v = xr[h * 128 + 8 * i + j];
            const float v2 = v * v;
            racc[j] = racc[j] + v2;
          }
        half[h] = ((racc[0] + racc[1]) + (racc[2] + racc[3])) +
                  ((racc[4] + racc[5]) + (racc[6] + racc[7]));
      }
      sxv = half[0] + half[1];
    }
    __syncthreads();
    float bv = FLT_MAX;
    int bi = 0x7FFFFFFF;
    for (int j = 0; j < 16; ++j) {
      const int k = j * 256 + t;
      const float* ek = cb + (size_t)k * CD;
      float a0 = 0.f, a1 = 0.f, a2 = 0.f, a3 = 0.f;
      for (int B = 0; B < 16; ++B)
        for (int jj = 3; jj >= 0; --jj) {
          const int c0 = 16 * B + 4 * jj;
          float p0 = xr[c0 + 0] * ek[c0 + 0]; a0 = a0 + p0;
          float p1 = xr[c0 + 1] * ek[c0 + 1]; a1 = a1 + p1;
          float p2 = xr[c0 + 2] * ek[c0 + 2]; a2 = a2 + p2;
          float p3 = xr[c0 + 3] * ek[c0 + 3]; a3 = a3 + p3;
        }
      const float dot = (a0 + a1) + (a2 + a3);
      const float dist = (se[k] + sxv) - 2.0f * dot;
      if (dist < bv || (dist == bv && k < bi)) { bv = dist; bi = k; }
    }
    rv[t] = bv; ri[t] = bi;
    __syncthreads();
    for (int off = 128; off > 0; off >>= 1) {
      if (t < off) {
        if (rv[t + off] < rv[t] || (rv[t + off] == rv[t] && ri[t + off] < ri[t])) {
          rv[t] = rv[t + off]; ri[t] = ri[t + off];
        }
      }
      __syncthreads();
    }
    if (t == 0) outids[row] = (float)ri[0];
  }
}

// ---------- emb gather [verified] ----------
__global__ __launch_bounds__(256) void vq_emb_out(const float* __restrict__ outids,
                                                  const float* __restrict__ cb,
                                                  float* __restrict__ out) {
  const int bx = blockIdx.x;
  const int b = bx >> 10;
  const int rem = bx & 1023;
  const int c = rem >> 2;
  const int q = rem & 3;
  const int hw = q * 256 + threadIdx.x;
  const int id = (int)outids[b * HW + hw];
  out[((size_t)(b * CD + c)) * HW + hw] = cb[(size_t)id * CD + c];
}

extern "C" void kernel_launch(void* const* d_in, const int* in_sizes, int n_in,
                              void* d_out, int out_size, void* d_ws, size_t ws_size,
                              hipStream_t stream) {
  const float* x  = (const float*)d_in[0];   // (32,256,32,32) f32
  const float* cb = (const float*)d_in[1];   // (4096,256) f32
  float* out = (float*)d_out;                // [0..32767]=ids, [32768..]=emb

  float* se = (float*)d_ws;                  // 16 KB

  // scratch inside the emb region (8,388,608 floats), overwritten last by gather
  float* sc = out + NRW;
  unsigned short* xh = (unsigned short*)sc;              // 16.8 MB
  unsigned short* eh = (unsigned short*)(sc + 4194304);  // 2.1 MB (pre-swizzled granules)
  int*   flg  = (int*)(sc + 4784128);                    // 32,768
  int*   nflg = (int*)(sc + 4816896);                    // 1

  vq_se<<<KC / 32, 256, 0, stream>>>(cb, se, nflg);
  vq_cvt_x<<<512, 256, 0, stream>>>(x, xh);
  vq_cvt_e<<<512, 256, 0, stream>>>(cb, eh);
  vq_gemm_fused<<<NRW / 32, 256, 0, stream>>>(xh, eh, se, x, cb, out, flg, nflg);
  vq_fallback<<<512, 256, 0, stream>>>(x, cb, se, flg, nflg, out);
  vq_emb_out<<<32768, 256, 0, stream>>>(out, cb, out + NRW);
}

// Round 22
// 395.654 us; speedup vs baseline: 1.6819x; 1.2089x over previous
//
#include <hip/hip_runtime.h>
#include <cfloat>

#define NRW 32768
#define KC 4096
#define CD 256
#define HW 1024
#define CAP 64
#define WINH 5e-4f   // dot-space window: 2*gamma + delta + se_max <= 4.5e-4 < WINH

typedef short bf16x8 __attribute__((ext_vector_type(8)));
typedef float f32x4 __attribute__((ext_vector_type(4)));

__device__ __forceinline__ unsigned short f2bf(float f) {  // RNE f32->bf16
  unsigned int u = __float_as_uint(f);
  u = (u + 0x7FFFu + ((u >> 16) & 1u)) >> 16;
  return (unsigned short)u;
}

// direct global->LDS 16B async copy [verified r17/r18]
__device__ __forceinline__ void gl2lds16(const unsigned short* g, unsigned short* l) {
  __builtin_amdgcn_global_load_lds(
      (const __attribute__((address_space(1))) void*)(const void*)g,
      (__attribute__((address_space(3))) void*)(void*)l, 16, 0, 0);
}

// max across each 16-lane DPP row, pure VALU [dppmin verified r16-r18; fmax variant]
__device__ __forceinline__ float dppmax16(float v) {
  float t;
  t = __uint_as_float(__builtin_amdgcn_update_dpp(0, __float_as_uint(v), 0xB1, 0xF, 0xF, true));
  v = fmaxf(v, t);
  t = __uint_as_float(__builtin_amdgcn_update_dpp(0, __float_as_uint(v), 0x4E, 0xF, 0xF, true));
  v = fmaxf(v, t);
  t = __uint_as_float(__builtin_amdgcn_update_dpp(0, __float_as_uint(v), 0x141, 0xF, 0xF, true));
  v = fmaxf(v, t);
  t = __uint_as_float(__builtin_amdgcn_update_dpp(0, __float_as_uint(v), 0x140, 0xF, 0xF, true));
  v = fmaxf(v, t);
  return v;
}

// ---------- se[k] = np.sum(cb[k]**2) : numpy pairwise [verified]; zeroes nflg ----------
__global__ __launch_bounds__(256) void vq_se(const float* __restrict__ cb,
                                             float* __restrict__ se,
                                             int* __restrict__ nflg) {
#pragma clang fp contract(off)
  const int tid = threadIdx.x;
  if (blockIdx.x == 0 && tid == 0) *nflg = 0;
  const int g = tid >> 3;
  const int j = tid & 7;
  const int code = blockIdx.x * 32 + g;
  const float* e = cb + (size_t)code * CD;
  float half[2];
#pragma unroll
  for (int h = 0; h < 2; ++h) {
    const float* a = e + h * 128;
    float v = a[j];
    float r = v * v;
#pragma unroll
    for (int i = 1; i < 16; ++i) {
      float w = a[8 * i + j];
      float w2 = w * w;
      r = r + w2;
    }
    float l1 = r + __shfl_down(r, 1, 8);
    float l2 = l1 + __shfl_down(l1, 2, 8);
    float l3 = l2 + __shfl_down(l2, 4, 8);
    half[h] = l3;
  }
  if (j == 0) se[code] = half[0] + half[1];
}

// ---------- convert x -> xh[row][ch] bf16 (transpose, RNE) [verified] ----------
__global__ __launch_bounds__(256) void vq_cvt_x(const float* __restrict__ x,
                                                unsigned short* __restrict__ xh) {
  const int t = threadIdx.x;                  // channel
  const int b = blockIdx.x >> 4;
  const int hw0 = (blockIdx.x & 15) << 6;
  const float* src = x + ((size_t)b * CD + t) * HW + hw0;
  unsigned short* dst = xh + ((size_t)b * HW + hw0) * CD + t;
#pragma unroll
  for (int f = 0; f < 16; ++f) {
    const float4 v = *(const float4*)(src + 4 * f);
    dst[(size_t)(4 * f + 0) * CD] = f2bf(v.x);
    dst[(size_t)(4 * f + 1) * CD] = f2bf(v.y);
    dst[(size_t)(4 * f + 2) * CD] = f2bf(v.z);
    dst[(size_t)(4 * f + 3) * CD] = f2bf(v.w);
  }
}

// ---------- convert cb -> eh PRE-SWIZZLED granule layout (32-code chunks) [verified r18] ----------
__global__ __launch_bounds__(256) void vq_cvt_e(const float* __restrict__ cb,
                                                unsigned short* __restrict__ eh) {
  const int gid = blockIdx.x * 256 + threadIdx.x;   // 131072 granules
  const int cg = gid >> 10;
  const int c8 = (gid >> 5) & 31;
  const int m  = gid & 31;
  const int code = (cg << 5) | (m ^ (c8 & 7));
  const float* s = cb + (size_t)code * CD + (c8 << 3);
  uint4 v;
  v.x = (unsigned)f2bf(s[0]) | ((unsigned)f2bf(s[1]) << 16);
  v.y = (unsigned)f2bf(s[2]) | ((unsigned)f2bf(s[3]) << 16);
  v.z = (unsigned)f2bf(s[4]) | ((unsigned)f2bf(s[5]) << 16);
  v.w = (unsigned)f2bf(s[6]) | ((unsigned)f2bf(s[7]) << 16);
  *(uint4*)(eh + (size_t)gid * 8) = v;
}

// ---------- MFMA filter GEMM: counted-vmcnt pipeline (T3/T4), LDS candidates ----------
// 64 rows/block (512 blocks = 2/CU); wave w: rows (w&1)*32 (2 slabs of 16), code half (w>>1)*16.
// es triple-buffered; per chunk: 4 gl2lds16 (the ONLY loop VMEM), 8 ds_read, 16 MFMA.
__global__ __launch_bounds__(256, 2) void vq_gemm(const unsigned short* __restrict__ xh,
                                                  const unsigned short* __restrict__ eh,
                                                  int* __restrict__ cnt,
                                                  int* __restrict__ cand) {
  __shared__ unsigned short esb[3 * 8192];   // 48 KB: 3 x (32 codes x 256 ch)
  __shared__ int candl[64 * CAP];            // 16 KB
  __shared__ int cntl[64];

  const int t = threadIdx.x;
  const int l = t & 63;
  const int w = t >> 6;
  const int rs = (w & 1) * 32;               // row-slab base (32 rows, 2 m-tiles)
  const int ch16 = (w >> 1) * 16;            // code half within 32-code chunk
  const int rowbase = blockIdx.x * 64;
  const int lq = l >> 4;
  const int ll = l & 15;

  if (t < 64) cntl[t] = 0;

  // A fragments: 2 m-tiles x 8 kb (resident, 64 VGPR)
  bf16x8 afr[2][8];
#pragma unroll
  for (int mt = 0; mt < 2; ++mt) {
    const unsigned short* ga = xh + (size_t)(rowbase + rs + 16 * mt + ll) * CD + (lq << 3);
#pragma unroll
    for (int kb = 0; kb < 8; ++kb)
      afr[mt][kb] = *(const bf16x8*)(ga + (kb << 5));
  }

  float run0[4], run1[4], rr0[4], rr1[4];
#pragma unroll
  for (int r = 0; r < 4; ++r) {
    run0[r] = -FLT_MAX; run1[r] = -FLT_MAX;
    rr0[r] = FLT_MAX;  rr1[r] = FLT_MAX;   // overwritten at q=0 before first collect
  }

  // stage a chunk into buffer buf (wave w covers c8 in [8w, 8w+8))
  auto STAGE = [&](int chunk, int buf) {
    const size_t cb0 = (size_t)chunk * 1024;   // granules per chunk
    unsigned short* db = esb + buf * 8192;
#pragma unroll
    for (int i = 0; i < 4; ++i) {
      const int gidx = (8 * w + 2 * i) * 32;
      gl2lds16(eh + (cb0 + gidx + l) * 8, db + (size_t)gidx * 8);
    }
  };

  // prologue: issue chunks 0 and 1 (8 loads outstanding)
  STAGE(0, 0);
  STAGE(1, 1);

  int cur = 0;
#pragma unroll 1
  for (int q = 0; q < 128; ++q) {
    // counted wait: chunk q's 4 loads done, chunk q+1's 4 may stay in flight.
    if (q != 127) {
      asm volatile("s_waitcnt vmcnt(4)\n\ts_barrier" ::: "memory");
    } else {
      asm volatile("s_waitcnt vmcnt(0)\n\ts_barrier" ::: "memory");
    }
    // stage chunk q+2 AFTER the barrier (all waves finished computing q-1 -> WAR-safe)
    if (q < 126) {
      int nb = cur + 2; if (nb >= 3) nb -= 3;
      STAGE(q + 2, nb);
    }

    // compute chunk q: 16 MFMA
    f32x4 acc0 = (f32x4){0.f, 0.f, 0.f, 0.f};
    f32x4 acc1 = (f32x4){0.f, 0.f, 0.f, 0.f};
    const unsigned short* eb = esb + cur * 8192;
#pragma unroll
    for (int kb = 0; kb < 8; ++kb) {
      const int c8 = (kb << 2) + lq;
      const int col = ch16 + ll;
      const bf16x8 bfr = *(const bf16x8*)&eb[((c8 << 5) + (col ^ (c8 & 7))) * 8];
      acc0 = __builtin_amdgcn_mfma_f32_16x16x32_bf16(afr[0][kb], bfr, acc0, 0, 0, 0);
      acc1 = __builtin_amdgcn_mfma_f32_16x16x32_bf16(afr[1][kb], bfr, acc1, 0, 0, 0);
    }

    // epilogue (dot space, se dropped: se_max 1.53e-5 absorbed by WINH):
    // running max; DPP row-tighten every 2nd chunk; collect dot >= max - WINH
#pragma unroll
    for (int r = 0; r < 4; ++r) {
      if (acc0[r] > run0[r]) run0[r] = acc0[r];
      if (acc1[r] > run1[r]) run1[r] = acc1[r];
    }
    if ((q & 1) == 0) {
#pragma unroll
      for (int r = 0; r < 4; ++r) {
        rr0[r] = dppmax16(run0[r]) - WINH;
        rr1[r] = dppmax16(run1[r]) - WINH;
      }
    }
#pragma unroll
    for (int r = 0; r < 4; ++r) {
      if (acc0[r] >= rr0[r]) {
        const int rowloc = rs + (lq << 2) + r;
        const int pos = atomicAdd(&cntl[rowloc], 1);
        if (pos < CAP) candl[rowloc * CAP + pos] = (q << 5) + ch16 + ll;
      }
      if (acc1[r] >= rr1[r]) {
        const int rowloc = rs + 16 + (lq << 2) + r;
        const int pos = atomicAdd(&cntl[rowloc], 1);
        if (pos < CAP) candl[rowloc * CAP + pos] = (q << 5) + ch16 + ll;
      }
    }
    ++cur; if (cur == 3) cur = 0;
  }

  // dump LDS candidates to global (pipeline done; full sync is fine here)
  __syncthreads();
#pragma unroll 1
  for (int idx = t; idx < 64 * CAP; idx += 256) {
    const int row = idx >> 6;          // CAP == 64
    const int pos = idx & 63;
    const int cn = cntl[row];
    if (pos < (cn < CAP ? cn : CAP))
      cand[(size_t)(rowbase + row) * CAP + pos] = candl[idx];
  }
  if (t < 64) cnt[rowbase + t] = cntl[t];
}

// ---------- np-exact recheck of candidates (8 rows/block, 32 lanes/row) [verified r17/r18] ----------
__global__ __launch_bounds__(256) void vq_recheck(const float* __restrict__ x,
                                                  const float* __restrict__ cb,
                                                  const float* __restrict__ se,
                                                  const int* __restrict__ cnt,
                                                  const int* __restrict__ cand,
                                                  float* __restrict__ outids,
                                                  int* __restrict__ flg,
                                                  int* __restrict__ nflg) {
#pragma clang fp contract(off)
  __shared__ float xr[8][256];
  __shared__ float sxs[8];
  const int t = threadIdx.x;
  const int r0 = blockIdx.x * 8;
  const int b = r0 >> 10, hw0 = r0 & 1023;
  {
    const float* px = x + ((size_t)b * CD + t) * HW + hw0;
    const float4 v0 = *(const float4*)(px);
    const float4 v1 = *(const float4*)(px + 4);
    xr[0][t] = v0.x; xr[1][t] = v0.y; xr[2][t] = v0.z; xr[3][t] = v0.w;
    xr[4][t] = v1.x; xr[5][t] = v1.y; xr[6][t] = v1.z; xr[7][t] = v1.w;
  }
  __syncthreads();
  if (t < 8) {   // np pairwise sx (verified order)
    float half[2];
#pragma unroll
    for (int h = 0; h < 2; ++h) {
      float racc[8];
#pragma unroll
      for (int j = 0; j < 8; ++j) { const float v = xr[t][h * 128 + j]; racc[j] = v * v; }
#pragma unroll
      for (int i = 1; i < 16; ++i)
#pragma unroll
        for (int j = 0; j < 8; ++j) {
          const float v = xr[t][h * 128 + 8 * i + j];
          const float v2 = v * v;
          racc[j] = racc[j] + v2;
        }
      half[h] = ((racc[0] + racc[1]) + (racc[2] + racc[3])) +
                ((racc[4] + racc[5]) + (racc[6] + racc[7]));
    }
    sxs[t] = half[0] + half[1];
  }
  __syncthreads();

  const int g = t >> 5, ln = t & 31;
  const int row = r0 + g;
  const int cn = cnt[row];
  float bv = FLT_MAX;
  int bi = 0x7FFFFFFF;
  if (cn > CAP) {
    if (ln == 0) { const int p = atomicAdd(nflg, 1); flg[p] = row; }
  } else {
    const float sx = sxs[g];
    const float* xrow = xr[g];
    for (int c = ln; c < cn; c += 32) {
      const int k = cand[(size_t)row * CAP + c];
      const float* ek = cb + (size_t)k * CD;
      float a0 = 0.f, a1 = 0.f, a2 = 0.f, a3 = 0.f;
      for (int B = 0; B < 16; ++B)
        for (int j = 3; j >= 0; --j) {
          const int c0 = 16 * B + 4 * j;
          float p0 = xrow[c0 + 0] * ek[c0 + 0]; a0 = a0 + p0;
          float p1 = xrow[c0 + 1] * ek[c0 + 1]; a1 = a1 + p1;
          float p2 = xrow[c0 + 2] * ek[c0 + 2]; a2 = a2 + p2;
          float p3 = xrow[c0 + 3] * ek[c0 + 3]; a3 = a3 + p3;
        }
      const float dot = (a0 + a1) + (a2 + a3);
      const float dist = (se[k] + sx) - 2.0f * dot;
      if (dist < bv || (dist == bv && k < bi)) { bv = dist; bi = k; }
    }
  }
#pragma unroll
  for (int off = 1; off < 32; off <<= 1) {
    const float ov = __shfl_xor(bv, off, 32);
    const int oi = __shfl_xor(bi, off, 32);
    if (ov < bv || (ov == bv && oi < bi)) { bv = ov; bi = oi; }
  }
  if (ln == 0 && cn <= CAP) outids[row] = (float)bi;
}

// ---------- full-row np-exact fallback for overflow rows [verified] ----------
__global__ __launch_bounds__(256) void vq_fallback(const float* __restrict__ x,
                                                   const float* __restrict__ cb,
                                                   const float* __restrict__ se,
                                                   const int* __restrict__ flg,
                                                   const int* __restrict__ nflg,
                                                   float* __restrict__ outids) {
#pragma clang fp contract(off)
  __shared__ float xr[256];
  __shared__ float sxv;
  __shared__ float rv[256];
  __shared__ int ri[256];
  const int t = threadIdx.x;
  const int nf = *nflg;
  for (int fi = blockIdx.x; fi < nf; fi += gridDim.x) {
    const int row = flg[fi];
    const int b = row >> 10, hw = row & 1023;
    __syncthreads();
    xr[t] = x[((size_t)b * CD + t) * HW + hw];
    __syncthreads();
    if (t == 0) {
      float half[2];
      for (int h = 0; h < 2; ++h) {
        float racc[8];
        for (int j = 0; j < 8; ++j) { const float v = xr[h * 128 + j]; racc[j] = v * v; }
        for (int i = 1; i < 16; ++i)
          for (int j = 0; j < 8; ++j) {
            const float v = xr[h * 128 + 8 * i + j];
            const float v2 = v * v;
            racc[j] = racc[j] + v2;
          }
        half[h] = ((racc[0] + racc[1]) + (racc[2] + racc[3])) +
                  ((racc[4] + racc[5]) + (racc[6] + racc[7]));
      }
      sxv = half[0] + half[1];
    }
    __syncthreads();
    float bv = FLT_MAX;
    int bi = 0x7FFFFFFF;
    for (int j = 0; j < 16; ++j) {
      const int k = j * 256 + t;
      const float* ek = cb + (size_t)k * CD;
      float a0 = 0.f, a1 = 0.f, a2 = 0.f, a3 = 0.f;
      for (int B = 0; B < 16; ++B)
        for (int jj = 3; jj >= 0; --jj) {
          const int c0 = 16 * B + 4 * jj;
          float p0 = xr[c0 + 0] * ek[c0 + 0]; a0 = a0 + p0;
          float p1 = xr[c0 + 1] * ek[c0 + 1]; a1 = a1 + p1;
          float p2 = xr[c0 + 2] * ek[c0 + 2]; a2 = a2 + p2;
          float p3 = xr[c0 + 3] * ek[c0 + 3]; a3 = a3 + p3;
        }
      const float dot = (a0 + a1) + (a2 + a3);
      const float dist = (se[k] + sxv) - 2.0f * dot;
      if (dist < bv || (dist == bv && k < bi)) { bv = dist; bi = k; }
    }
    rv[t] = bv; ri[t] = bi;
    __syncthreads();
    for (int off = 128; off > 0; off >>= 1) {
      if (t < off) {
        if (rv[t + off] < rv[t] || (rv[t + off] == rv[t] && ri[t + off] < ri[t])) {
          rv[t] = rv[t + off]; ri[t] = ri[t + off];
        }
      }
      __syncthreads();
    }
    if (t == 0) outids[row] = (float)ri[0];
  }
}

// ---------- emb gather [verified] ----------
__global__ __launch_bounds__(256) void vq_emb_out(const float* __restrict__ outids,
                                                  const float* __restrict__ cb,
                                                  float* __restrict__ out) {
  const int bx = blockIdx.x;
  const int b = bx >> 10;
  const int rem = bx & 1023;
  const int c = rem >> 2;
  const int q = rem & 3;
  const int hw = q * 256 + threadIdx.x;
  const int id = (int)outids[b * HW + hw];
  out[((size_t)(b * CD + c)) * HW + hw] = cb[(size_t)id * CD + c];
}

extern "C" void kernel_launch(void* const* d_in, const int* in_sizes, int n_in,
                              void* d_out, int out_size, void* d_ws, size_t ws_size,
                              hipStream_t stream) {
  const float* x  = (const float*)d_in[0];   // (32,256,32,32) f32
  const float* cb = (const float*)d_in[1];   // (4096,256) f32
  float* out = (float*)d_out;                // [0..32767]=ids, [32768..]=emb

  float* se = (float*)d_ws;                  // 16 KB

  // scratch inside the emb region (8,388,608 floats), overwritten last by gather
  float* sc = out + NRW;
  unsigned short* xh = (unsigned short*)sc;              // 16.8 MB
  unsigned short* eh = (unsigned short*)(sc + 4194304);  // 2.1 MB (pre-swizzled granules)
  int*   cnt  = (int*)(sc + 4751360);                    // 32,768
  int*   flg  = (int*)(sc + 4784128);                    // 32,768
  int*   nflg = (int*)(sc + 4816896);                    // 1
  int*   cand = (int*)(sc + 4816960);                    // 32768*64 ints

  vq_se<<<KC / 32, 256, 0, stream>>>(cb, se, nflg);
  vq_cvt_x<<<512, 256, 0, stream>>>(x, xh);
  vq_cvt_e<<<512, 256, 0, stream>>>(cb, eh);
  vq_gemm<<<NRW / 64, 256, 0, stream>>>(xh, eh, cnt, cand);
  vq_recheck<<<NRW / 8, 256, 0, stream>>>(x, cb, se, cnt, cand, out, flg, nflg);
  vq_fallback<<<512, 256, 0, stream>>>(x, cb, se, flg, nflg, out);
  vq_emb_out<<<32768, 256, 0, stream>>>(out, cb, out + NRW);
}

// Round 23
// 369.746 us; speedup vs baseline: 1.7997x; 1.0701x over previous
//
#include <hip/hip_runtime.h>
#include <cfloat>

#define NRW 32768
#define KC 4096
#define CD 256
#define HW 1024
#define CAP 64
#define WINH 5e-4f   // dot-space window: 2*gamma + delta + se_max <= 4.5e-4 < WINH
#define XPAD 258

typedef short bf16x8 __attribute__((ext_vector_type(8)));
typedef float f32x4 __attribute__((ext_vector_type(4)));

__device__ __forceinline__ unsigned short f2bf(float f) {  // RNE f32->bf16
  unsigned int u = __float_as_uint(f);
  u = (u + 0x7FFFu + ((u >> 16) & 1u)) >> 16;
  return (unsigned short)u;
}

// direct global->LDS 16B async copy [verified r17/r18]
__device__ __forceinline__ void gl2lds16(const unsigned short* g, unsigned short* l) {
  __builtin_amdgcn_global_load_lds(
      (const __attribute__((address_space(1))) void*)(const void*)g,
      (__attribute__((address_space(3))) void*)(void*)l, 16, 0, 0);
}

// max across each 16-lane DPP row, pure VALU [verified r22]
__device__ __forceinline__ float dppmax16(float v) {
  float t;
  t = __uint_as_float(__builtin_amdgcn_update_dpp(0, __float_as_uint(v), 0xB1, 0xF, 0xF, true));
  v = fmaxf(v, t);
  t = __uint_as_float(__builtin_amdgcn_update_dpp(0, __float_as_uint(v), 0x4E, 0xF, 0xF, true));
  v = fmaxf(v, t);
  t = __uint_as_float(__builtin_amdgcn_update_dpp(0, __float_as_uint(v), 0x141, 0xF, 0xF, true));
  v = fmaxf(v, t);
  t = __uint_as_float(__builtin_amdgcn_update_dpp(0, __float_as_uint(v), 0x140, 0xF, 0xF, true));
  v = fmaxf(v, t);
  return v;
}

// ---------- se[k] = np.sum(cb[k]**2) : numpy pairwise [verified]; zeroes nflg ----------
__global__ __launch_bounds__(256) void vq_se(const float* __restrict__ cb,
                                             float* __restrict__ se,
                                             int* __restrict__ nflg) {
#pragma clang fp contract(off)
  const int tid = threadIdx.x;
  if (blockIdx.x == 0 && tid == 0) *nflg = 0;
  const int g = tid >> 3;
  const int j = tid & 7;
  const int code = blockIdx.x * 32 + g;
  const float* e = cb + (size_t)code * CD;
  float half[2];
#pragma unroll
  for (int h = 0; h < 2; ++h) {
    const float* a = e + h * 128;
    float v = a[j];
    float r = v * v;
#pragma unroll
    for (int i = 1; i < 16; ++i) {
      float w = a[8 * i + j];
      float w2 = w * w;
      r = r + w2;
    }
    float l1 = r + __shfl_down(r, 1, 8);
    float l2 = l1 + __shfl_down(l1, 2, 8);
    float l3 = l2 + __shfl_down(l2, 4, 8);
    half[h] = l3;
  }
  if (j == 0) se[code] = half[0] + half[1];
}

// ---------- convert x -> xh[row][ch] bf16 (transpose, RNE) [verified] ----------
__global__ __launch_bounds__(256) void vq_cvt_x(const float* __restrict__ x,
                                                unsigned short* __restrict__ xh) {
  const int t = threadIdx.x;                  // channel
  const int b = blockIdx.x >> 4;
  const int hw0 = (blockIdx.x & 15) << 6;
  const float* src = x + ((size_t)b * CD + t) * HW + hw0;
  unsigned short* dst = xh + ((size_t)b * HW + hw0) * CD + t;
#pragma unroll
  for (int f = 0; f < 16; ++f) {
    const float4 v = *(const float4*)(src + 4 * f);
    dst[(size_t)(4 * f + 0) * CD] = f2bf(v.x);
    dst[(size_t)(4 * f + 1) * CD] = f2bf(v.y);
    dst[(size_t)(4 * f + 2) * CD] = f2bf(v.z);
    dst[(size_t)(4 * f + 3) * CD] = f2bf(v.w);
  }
}

// ---------- convert cb -> eh PRE-SWIZZLED granule layout (32-code chunks) [verified r18] ----------
__global__ __launch_bounds__(256) void vq_cvt_e(const float* __restrict__ cb,
                                                unsigned short* __restrict__ eh) {
  const int gid = blockIdx.x * 256 + threadIdx.x;   // 131072 granules
  const int cg = gid >> 10;
  const int c8 = (gid >> 5) & 31;
  const int m  = gid & 31;
  const int code = (cg << 5) | (m ^ (c8 & 7));
  const float* s = cb + (size_t)code * CD + (c8 << 3);
  uint4 v;
  v.x = (unsigned)f2bf(s[0]) | ((unsigned)f2bf(s[1]) << 16);
  v.y = (unsigned)f2bf(s[2]) | ((unsigned)f2bf(s[3]) << 16);
  v.z = (unsigned)f2bf(s[4]) | ((unsigned)f2bf(s[5]) << 16);
  v.w = (unsigned)f2bf(s[6]) | ((unsigned)f2bf(s[7]) << 16);
  *(uint4*)(eh + (size_t)gid * 8) = v;
}

// ---------- MFMA filter GEMM: counted-vmcnt pipeline, LDS candidates [verified r22] ----------
__global__ __launch_bounds__(256, 2) void vq_gemm(const unsigned short* __restrict__ xh,
                                                  const unsigned short* __restrict__ eh,
                                                  int* __restrict__ cnt,
                                                  int* __restrict__ cand) {
  __shared__ unsigned short esb[3 * 8192];   // 48 KB: 3 x (32 codes x 256 ch)
  __shared__ int candl[64 * CAP];            // 16 KB
  __shared__ int cntl[64];

  const int t = threadIdx.x;
  const int l = t & 63;
  const int w = t >> 6;
  const int rs = (w & 1) * 32;
  const int ch16 = (w >> 1) * 16;
  const int rowbase = blockIdx.x * 64;
  const int lq = l >> 4;
  const int ll = l & 15;

  if (t < 64) cntl[t] = 0;

  bf16x8 afr[2][8];
#pragma unroll
  for (int mt = 0; mt < 2; ++mt) {
    const unsigned short* ga = xh + (size_t)(rowbase + rs + 16 * mt + ll) * CD + (lq << 3);
#pragma unroll
    for (int kb = 0; kb < 8; ++kb)
      afr[mt][kb] = *(const bf16x8*)(ga + (kb << 5));
  }

  float run0[4], run1[4], rr0[4], rr1[4];
#pragma unroll
  for (int r = 0; r < 4; ++r) {
    run0[r] = -FLT_MAX; run1[r] = -FLT_MAX;
    rr0[r] = FLT_MAX;  rr1[r] = FLT_MAX;
  }

  auto STAGE = [&](int chunk, int buf) {
    const size_t cb0 = (size_t)chunk * 1024;
    unsigned short* db = esb + buf * 8192;
#pragma unroll
    for (int i = 0; i < 4; ++i) {
      const int gidx = (8 * w + 2 * i) * 32;
      gl2lds16(eh + (cb0 + gidx + l) * 8, db + (size_t)gidx * 8);
    }
  };

  STAGE(0, 0);
  STAGE(1, 1);

  int cur = 0;
#pragma unroll 1
  for (int q = 0; q < 128; ++q) {
    if (q != 127) {
      asm volatile("s_waitcnt vmcnt(4)\n\ts_barrier" ::: "memory");
    } else {
      asm volatile("s_waitcnt vmcnt(0)\n\ts_barrier" ::: "memory");
    }
    if (q < 126) {
      int nb = cur + 2; if (nb >= 3) nb -= 3;
      STAGE(q + 2, nb);
    }

    f32x4 acc0 = (f32x4){0.f, 0.f, 0.f, 0.f};
    f32x4 acc1 = (f32x4){0.f, 0.f, 0.f, 0.f};
    const unsigned short* eb = esb + cur * 8192;
#pragma unroll
    for (int kb = 0; kb < 8; ++kb) {
      const int c8 = (kb << 2) + lq;
      const int col = ch16 + ll;
      const bf16x8 bfr = *(const bf16x8*)&eb[((c8 << 5) + (col ^ (c8 & 7))) * 8];
      acc0 = __builtin_amdgcn_mfma_f32_16x16x32_bf16(afr[0][kb], bfr, acc0, 0, 0, 0);
      acc1 = __builtin_amdgcn_mfma_f32_16x16x32_bf16(afr[1][kb], bfr, acc1, 0, 0, 0);
    }

#pragma unroll
    for (int r = 0; r < 4; ++r) {
      if (acc0[r] > run0[r]) run0[r] = acc0[r];
      if (acc1[r] > run1[r]) run1[r] = acc1[r];
    }
    if ((q & 1) == 0) {
#pragma unroll
      for (int r = 0; r < 4; ++r) {
        rr0[r] = dppmax16(run0[r]) - WINH;
        rr1[r] = dppmax16(run1[r]) - WINH;
      }
    }
#pragma unroll
    for (int r = 0; r < 4; ++r) {
      if (acc0[r] >= rr0[r]) {
        const int rowloc = rs + (lq << 2) + r;
        const int pos = atomicAdd(&cntl[rowloc], 1);
        if (pos < CAP) candl[rowloc * CAP + pos] = (q << 5) + ch16 + ll;
      }
      if (acc1[r] >= rr1[r]) {
        const int rowloc = rs + 16 + (lq << 2) + r;
        const int pos = atomicAdd(&cntl[rowloc], 1);
        if (pos < CAP) candl[rowloc * CAP + pos] = (q << 5) + ch16 + ll;
      }
    }
    ++cur; if (cur == 3) cur = 0;
  }

  __syncthreads();
#pragma unroll 1
  for (int idx = t; idx < 64 * CAP; idx += 256) {
    const int row = idx >> 6;
    const int pos = idx & 63;
    const int cn = cntl[row];
    if (pos < (cn < CAP ? cn : CAP))
      cand[(size_t)(rowbase + row) * CAP + pos] = candl[idx];
  }
  if (t < 64) cnt[rowbase + t] = cntl[t];
}

// ---------- np-exact recheck: 32 rows/block, line-perfect x staging, cn==1 shortcut ----------
__global__ __launch_bounds__(256, 2) void vq_recheck(const float* __restrict__ x,
                                                     const float* __restrict__ cb,
                                                     const float* __restrict__ se,
                                                     const int* __restrict__ cnt,
                                                     const int* __restrict__ cand,
                                                     float* __restrict__ outids,
                                                     int* __restrict__ flg,
                                                     int* __restrict__ nflg) {
#pragma clang fp contract(off)
  __shared__ float xr[32 * XPAD];    // 33 KB
  __shared__ float sxs[32];
  const int t = threadIdx.x;
  const int rowbase = blockIdx.x * 32;
  const int b = rowbase >> 10, hw0 = rowbase & 1023;

  // stage x: thread = channel, 32 consecutive hw floats = one 128B line (coalesced, 0 waste)
  {
    const float* px = x + ((size_t)b * CD + t) * HW + hw0;
#pragma unroll
    for (int f = 0; f < 8; ++f) {
      const float4 v = *(const float4*)(px + 4 * f);
      xr[(4 * f + 0) * XPAD + t] = v.x;
      xr[(4 * f + 1) * XPAD + t] = v.y;
      xr[(4 * f + 2) * XPAD + t] = v.z;
      xr[(4 * f + 3) * XPAD + t] = v.w;
    }
  }
  __syncthreads();

  // sx per row: numpy pairwise (128+128, 8-lane group tree) [verified r21]
  {
    const int g = t >> 3, j = t & 7;
    float half[2];
#pragma unroll
    for (int h = 0; h < 2; ++h) {
      const float* a = xr + g * XPAD + h * 128;
      float v = a[j];
      float r = v * v;
#pragma unroll
      for (int i = 1; i < 16; ++i) {
        float ww = a[8 * i + j];
        float w2 = ww * ww;
        r = r + w2;
      }
      float l1 = r + __shfl_down(r, 1, 8);
      float l2 = l1 + __shfl_down(l1, 2, 8);
      float l3 = l2 + __shfl_down(l2, 4, 8);
      half[h] = l3;
    }
    if (j == 0) sxs[g] = half[0] + half[1];
  }
  __syncthreads();

  // recheck: 8 lanes per row [verified r21 tail]; cn==1 shortcut
  {
    const int g = t >> 3, j = t & 7;
    const int row = rowbase + g;
    const int cn = cnt[row];
    if (cn > CAP) {
      if (j == 0) { const int p = atomicAdd(nflg, 1); flg[p] = row; }
    } else if (cn == 1) {
      if (j == 0) outids[row] = (float)cand[(size_t)row * CAP];
    } else {
      float bv = FLT_MAX;
      int bi = 0x7FFFFFFF;
      const float sx = sxs[g];
      const float* xrow = xr + g * XPAD;
      for (int c = j; c < cn; c += 8) {
        const int k = cand[(size_t)row * CAP + c];
        const float* ek = cb + (size_t)k * CD;
        float a0 = 0.f, a1 = 0.f, a2 = 0.f, a3 = 0.f;
        for (int B = 0; B < 16; ++B)
          for (int jj = 3; jj >= 0; --jj) {
            const int c0 = 16 * B + 4 * jj;
            float p0 = xrow[c0 + 0] * ek[c0 + 0]; a0 = a0 + p0;
            float p1 = xrow[c0 + 1] * ek[c0 + 1]; a1 = a1 + p1;
            float p2 = xrow[c0 + 2] * ek[c0 + 2]; a2 = a2 + p2;
            float p3 = xrow[c0 + 3] * ek[c0 + 3]; a3 = a3 + p3;
          }
        const float dot = (a0 + a1) + (a2 + a3);
        const float dist = (se[k] + sx) - 2.0f * dot;
        if (dist < bv || (dist == bv && k < bi)) { bv = dist; bi = k; }
      }
#pragma unroll
      for (int off = 1; off < 8; off <<= 1) {
        const float ov = __shfl_xor(bv, off, 8);
        const int oi = __shfl_xor(bi, off, 8);
        if (ov < bv || (ov == bv && oi < bi)) { bv = ov; bi = oi; }
      }
      if (j == 0) outids[row] = (float)bi;
    }
  }
}

// ---------- full-row np-exact fallback for overflow rows [verified] ----------
__global__ __launch_bounds__(256) void vq_fallback(const float* __restrict__ x,
                                                   const float* __restrict__ cb,
                                                   const float* __restrict__ se,
                                                   const int* __restrict__ flg,
                                                   const int* __restrict__ nflg,
                                                   float* __restrict__ outids) {
#pragma clang fp contract(off)
  __shared__ float xr[256];
  __shared__ float sxv;
  __shared__ float rv[256];
  __shared__ int ri[256];
  const int t = threadIdx.x;
  const int nf = *nflg;
  for (int fi = blockIdx.x; fi < nf; fi += gridDim.x) {
    const int row = flg[fi];
    const int b = row >> 10, hw = row & 1023;
    __syncthreads();
    xr[t] = x[((size_t)b * CD + t) * HW + hw];
    __syncthreads();
    if (t == 0) {
      float half[2];
      for (int h = 0; h < 2; ++h) {
        float racc[8];
        for (int j = 0; j < 8; ++j) { const float v = xr[h * 128 + j]; racc[j] = v * v; }
        for (int i = 1; i < 16; ++i)
          for (int j = 0; j < 8; ++j) {
            const float v = xr[h * 128 + 8 * i + j];
            const float v2 = v * v;
            racc[j] = racc[j] + v2;
          }
        half[h] = ((racc[0] + racc[1]) + (racc[2] + racc[3])) +
                  ((racc[4] + racc[5]) + (racc[6] + racc[7]));
      }
      sxv = half[0] + half[1];
    }
    __syncthreads();
    float bv = FLT_MAX;
    int bi = 0x7FFFFFFF;
    for (int j = 0; j < 16; ++j) {
      const int k = j * 256 + t;
      const float* ek = cb + (size_t)k * CD;
      float a0 = 0.f, a1 = 0.f, a2 = 0.f, a3 = 0.f;
      for (int B = 0; B < 16; ++B)
        for (int jj = 3; jj >= 0; --jj) {
          const int c0 = 16 * B + 4 * jj;
          float p0 = xr[c0 + 0] * ek[c0 + 0]; a0 = a0 + p0;
          float p1 = xr[c0 + 1] * ek[c0 + 1]; a1 = a1 + p1;
          float p2 = xr[c0 + 2] * ek[c0 + 2]; a2 = a2 + p2;
          float p3 = xr[c0 + 3] * ek[c0 + 3]; a3 = a3 + p3;
        }
      const float dot = (a0 + a1) + (a2 + a3);
      const float dist = (se[k] + sxv) - 2.0f * dot;
      if (dist < bv || (dist == bv && k < bi)) { bv = dist; bi = k; }
    }
    rv[t] = bv; ri[t] = bi;
    __syncthreads();
    for (int off = 128; off > 0; off >>= 1) {
      if (t < off) {
        if (rv[t + off] < rv[t] || (rv[t + off] == rv[t] && ri[t + off] < ri[t])) {
          rv[t] = rv[t + off]; ri[t] = ri[t + off];
        }
      }
      __syncthreads();
    }
    if (t == 0) outids[row] = (float)ri[0];
  }
}

// ---------- emb gather [verified] ----------
__global__ __launch_bounds__(256) void vq_emb_out(const float* __restrict__ outids,
                                                  const float* __restrict__ cb,
                                                  float* __restrict__ out) {
  const int bx = blockIdx.x;
  const int b = bx >> 10;
  const int rem = bx & 1023;
  const int c = rem >> 2;
  const int q = rem & 3;
  const int hw = q * 256 + threadIdx.x;
  const int id = (int)outids[b * HW + hw];
  out[((size_t)(b * CD + c)) * HW + hw] = cb[(size_t)id * CD + c];
}

extern "C" void kernel_launch(void* const* d_in, const int* in_sizes, int n_in,
                              void* d_out, int out_size, void* d_ws, size_t ws_size,
                              hipStream_t stream) {
  const float* x  = (const float*)d_in[0];   // (32,256,32,32) f32
  const float* cb = (const float*)d_in[1];   // (4096,256) f32
  float* out = (float*)d_out;                // [0..32767]=ids, [32768..]=emb

  float* se = (float*)d_ws;                  // 16 KB

  // scratch inside the emb region (8,388,608 floats), overwritten last by gather
  float* sc = out + NRW;
  unsigned short* xh = (unsigned short*)sc;              // 16.8 MB
  unsigned short* eh = (unsigned short*)(sc + 4194304);  // 2.1 MB (pre-swizzled granules)
  int*   cnt  = (int*)(sc + 4751360);                    // 32,768
  int*   flg  = (int*)(sc + 4784128);                    // 32,768
  int*   nflg = (int*)(sc + 4816896);                    // 1
  int*   cand = (int*)(sc + 4816960);                    // 32768*64 ints

  vq_se<<<KC / 32, 256, 0, stream>>>(cb, se, nflg);
  vq_cvt_x<<<512, 256, 0, stream>>>(x, xh);
  vq_cvt_e<<<512, 256, 0, stream>>>(cb, eh);
  vq_gemm<<<NRW / 64, 256, 0, stream>>>(xh, eh, cnt, cand);
  vq_recheck<<<NRW / 32, 256, 0, stream>>>(x, cb, se, cnt, cand, out, flg, nflg);
  vq_fallback<<<512, 256, 0, stream>>>(x, cb, se, flg, nflg, out);
  vq_emb_out<<<32768, 256, 0, stream>>>(out, cb, out + NRW);
}

// Round 24
// 272.200 us; speedup vs baseline: 2.4447x; 1.3584x over previous
//
#include <hip/hip_runtime.h>
#include <cfloat>

#define NRW 32768
#define KC 4096
#define CD 256
#define HW 1024
#define CAP 64
#define WINH 5e-4f   // dot-space window: 2*gamma + delta + se_max <= 4.5e-4 < WINH
#define XPAD 258

typedef short bf16x8 __attribute__((ext_vector_type(8)));
typedef float f32x4 __attribute__((ext_vector_type(4)));

__device__ __forceinline__ unsigned short f2bf(float f) {  // RNE f32->bf16
  unsigned int u = __float_as_uint(f);
  u = (u + 0x7FFFu + ((u >> 16) & 1u)) >> 16;
  return (unsigned short)u;
}

// monotonic float->uint (order-preserving), and inverse
__device__ __forceinline__ unsigned flipf(float f) {
  unsigned u = __float_as_uint(f);
  return u ^ (unsigned)(((int)u >> 31) | 0x80000000);
}
__device__ __forceinline__ float unflipf(unsigned m) {
  return (m & 0x80000000u) ? __uint_as_float(m ^ 0x80000000u) : __uint_as_float(~m);
}

// direct global->LDS 16B async copy [verified r17/r18]
__device__ __forceinline__ void gl2lds16(const unsigned short* g, unsigned short* l) {
  __builtin_amdgcn_global_load_lds(
      (const __attribute__((address_space(1))) void*)(const void*)g,
      (__attribute__((address_space(3))) void*)(void*)l, 16, 0, 0);
}

// max across each 16-lane DPP row, pure VALU [verified r22]
__device__ __forceinline__ float dppmax16(float v) {
  float t;
  t = __uint_as_float(__builtin_amdgcn_update_dpp(0, __float_as_uint(v), 0xB1, 0xF, 0xF, true));
  v = fmaxf(v, t);
  t = __uint_as_float(__builtin_amdgcn_update_dpp(0, __float_as_uint(v), 0x4E, 0xF, 0xF, true));
  v = fmaxf(v, t);
  t = __uint_as_float(__builtin_amdgcn_update_dpp(0, __float_as_uint(v), 0x141, 0xF, 0xF, true));
  v = fmaxf(v, t);
  t = __uint_as_float(__builtin_amdgcn_update_dpp(0, __float_as_uint(v), 0x140, 0xF, 0xF, true));
  v = fmaxf(v, t);
  return v;
}

// ---------- se[k] = np.sum(cb[k]**2) : numpy pairwise [verified]; zeroes nflg ----------
__global__ __launch_bounds__(256) void vq_se(const float* __restrict__ cb,
                                             float* __restrict__ se,
                                             int* __restrict__ nflg) {
#pragma clang fp contract(off)
  const int tid = threadIdx.x;
  if (blockIdx.x == 0 && tid == 0) *nflg = 0;
  const int g = tid >> 3;
  const int j = tid & 7;
  const int code = blockIdx.x * 32 + g;
  const float* e = cb + (size_t)code * CD;
  float half[2];
#pragma unroll
  for (int h = 0; h < 2; ++h) {
    const float* a = e + h * 128;
    float v = a[j];
    float r = v * v;
#pragma unroll
    for (int i = 1; i < 16; ++i) {
      float w = a[8 * i + j];
      float w2 = w * w;
      r = r + w2;
    }
    float l1 = r + __shfl_down(r, 1, 8);
    float l2 = l1 + __shfl_down(l1, 2, 8);
    float l3 = l2 + __shfl_down(l2, 4, 8);
    half[h] = l3;
  }
  if (j == 0) se[code] = half[0] + half[1];
}

// ---------- convert x -> xh[row][ch] bf16 (transpose, RNE) [verified] ----------
__global__ __launch_bounds__(256) void vq_cvt_x(const float* __restrict__ x,
                                                unsigned short* __restrict__ xh) {
  const int t = threadIdx.x;                  // channel
  const int b = blockIdx.x >> 4;
  const int hw0 = (blockIdx.x & 15) << 6;
  const float* src = x + ((size_t)b * CD + t) * HW + hw0;
  unsigned short* dst = xh + ((size_t)b * HW + hw0) * CD + t;
#pragma unroll
  for (int f = 0; f < 16; ++f) {
    const float4 v = *(const float4*)(src + 4 * f);
    dst[(size_t)(4 * f + 0) * CD] = f2bf(v.x);
    dst[(size_t)(4 * f + 1) * CD] = f2bf(v.y);
    dst[(size_t)(4 * f + 2) * CD] = f2bf(v.z);
    dst[(size_t)(4 * f + 3) * CD] = f2bf(v.w);
  }
}

// ---------- convert cb -> eh PRE-SWIZZLED granule layout (32-code chunks) [verified r18] ----------
__global__ __launch_bounds__(256) void vq_cvt_e(const float* __restrict__ cb,
                                                unsigned short* __restrict__ eh) {
  const int gid = blockIdx.x * 256 + threadIdx.x;   // 131072 granules
  const int cg = gid >> 10;
  const int c8 = (gid >> 5) & 31;
  const int m  = gid & 31;
  const int code = (cg << 5) | (m ^ (c8 & 7));
  const float* s = cb + (size_t)code * CD + (c8 << 3);
  uint4 v;
  v.x = (unsigned)f2bf(s[0]) | ((unsigned)f2bf(s[1]) << 16);
  v.y = (unsigned)f2bf(s[2]) | ((unsigned)f2bf(s[3]) << 16);
  v.z = (unsigned)f2bf(s[4]) | ((unsigned)f2bf(s[5]) << 16);
  v.w = (unsigned)f2bf(s[6]) | ((unsigned)f2bf(s[7]) << 16);
  *(uint4*)(eh + (size_t)gid * 8) = v;
}

// ---------- MFMA filter GEMM: counted-vmcnt pipeline [verified r22/r23] ----------
// NEW: candl stores (flip(dot)&0xFFFFF000)|code; dump re-filters vs FINAL cross-wave
// threshold (maxsh atomicMax) -> only true-window candidates reach global memory.
__global__ __launch_bounds__(256, 2) void vq_gemm(const unsigned short* __restrict__ xh,
                                                  const unsigned short* __restrict__ eh,
                                                  int* __restrict__ cnt,
                                                  int* __restrict__ cand) {
  __shared__ unsigned short esb[3 * 8192];   // 48 KB: 3 x (32 codes x 256 ch)
  __shared__ unsigned candl[64 * CAP];       // 16 KB (packed dot|code)
  __shared__ int cntl[64];
  __shared__ unsigned maxsh[64];             // flip(global max dot) per row

  const int t = threadIdx.x;
  const int l = t & 63;
  const int w = t >> 6;
  const int rs = (w & 1) * 32;
  const int ch16 = (w >> 1) * 16;
  const int rowbase = blockIdx.x * 64;
  const int lq = l >> 4;
  const int ll = l & 15;

  if (t < 64) { cntl[t] = 0; maxsh[t] = 0u; }

  bf16x8 afr[2][8];
#pragma unroll
  for (int mt = 0; mt < 2; ++mt) {
    const unsigned short* ga = xh + (size_t)(rowbase + rs + 16 * mt + ll) * CD + (lq << 3);
#pragma unroll
    for (int kb = 0; kb < 8; ++kb)
      afr[mt][kb] = *(const bf16x8*)(ga + (kb << 5));
  }

  float run0[4], run1[4], rr0[4], rr1[4];
#pragma unroll
  for (int r = 0; r < 4; ++r) {
    run0[r] = -FLT_MAX; run1[r] = -FLT_MAX;
    rr0[r] = FLT_MAX;  rr1[r] = FLT_MAX;
  }

  auto STAGE = [&](int chunk, int buf) {
    const size_t cb0 = (size_t)chunk * 1024;
    unsigned short* db = esb + buf * 8192;
#pragma unroll
    for (int i = 0; i < 4; ++i) {
      const int gidx = (8 * w + 2 * i) * 32;
      gl2lds16(eh + (cb0 + gidx + l) * 8, db + (size_t)gidx * 8);
    }
  };

  STAGE(0, 0);
  STAGE(1, 1);

  int cur = 0;
#pragma unroll 1
  for (int q = 0; q < 128; ++q) {
    if (q != 127) {
      asm volatile("s_waitcnt vmcnt(4)\n\ts_barrier" ::: "memory");
    } else {
      asm volatile("s_waitcnt vmcnt(0)\n\ts_barrier" ::: "memory");
    }
    if (q < 126) {
      int nb = cur + 2; if (nb >= 3) nb -= 3;
      STAGE(q + 2, nb);
    }

    f32x4 acc0 = (f32x4){0.f, 0.f, 0.f, 0.f};
    f32x4 acc1 = (f32x4){0.f, 0.f, 0.f, 0.f};
    const unsigned short* eb = esb + cur * 8192;
#pragma unroll
    for (int kb = 0; kb < 8; ++kb) {
      const int c8 = (kb << 2) + lq;
      const int col = ch16 + ll;
      const bf16x8 bfr = *(const bf16x8*)&eb[((c8 << 5) + (col ^ (c8 & 7))) * 8];
      acc0 = __builtin_amdgcn_mfma_f32_16x16x32_bf16(afr[0][kb], bfr, acc0, 0, 0, 0);
      acc1 = __builtin_amdgcn_mfma_f32_16x16x32_bf16(afr[1][kb], bfr, acc1, 0, 0, 0);
    }

#pragma unroll
    for (int r = 0; r < 4; ++r) {
      if (acc0[r] > run0[r]) run0[r] = acc0[r];
      if (acc1[r] > run1[r]) run1[r] = acc1[r];
    }
    if ((q & 1) == 0) {
#pragma unroll
      for (int r = 0; r < 4; ++r) {
        rr0[r] = dppmax16(run0[r]) - WINH;
        rr1[r] = dppmax16(run1[r]) - WINH;
      }
    }
    const unsigned codebits = (unsigned)((q << 5) + ch16 + ll);
#pragma unroll
    for (int r = 0; r < 4; ++r) {
      if (acc0[r] >= rr0[r]) {
        const int rowloc = rs + (lq << 2) + r;
        const int pos = atomicAdd(&cntl[rowloc], 1);
        if (pos < CAP) candl[rowloc * CAP + pos] = (flipf(acc0[r]) & 0xFFFFF000u) | codebits;
      }
      if (acc1[r] >= rr1[r]) {
        const int rowloc = rs + 16 + (lq << 2) + r;
        const int pos = atomicAdd(&cntl[rowloc], 1);
        if (pos < CAP) candl[rowloc * CAP + pos] = (flipf(acc1[r]) & 0xFFFFF000u) | codebits;
      }
    }
    ++cur; if (cur == 3) cur = 0;
  }

  // contribute final half-maxes to maxsh (cross-wave global max per row)
  {
    float f0[4], f1[4];
#pragma unroll
    for (int r = 0; r < 4; ++r) { f0[r] = dppmax16(run0[r]); f1[r] = dppmax16(run1[r]); }
    if (ll == 0) {
#pragma unroll
      for (int r = 0; r < 4; ++r) {
        atomicMax(&maxsh[rs + (lq << 2) + r], flipf(f0[r]));
        atomicMax(&maxsh[rs + 16 + (lq << 2) + r], flipf(f1[r]));
      }
    }
  }
  __syncthreads();

  // dump: re-filter against FINAL threshold gm - WINH (one-quantum slack), compact
  if (t < 64) {
    const int cn = cntl[t];
    const float gm = unflipf(maxsh[t]);
    const unsigned tp = flipf(gm - WINH) & 0xFFFFF000u;
    const int lim = cn < CAP ? cn : CAP;
    int kept = 0;
    for (int pos = 0; pos < lim; ++pos) {
      const unsigned pk = candl[t * CAP + pos];
      if ((pk & 0xFFFFF000u) + 0x1000u >= tp)
        cand[(size_t)(rowbase + t) * CAP + (kept++)] = (int)(pk & 0xFFFu);
    }
    cnt[rowbase + t] = (cn > CAP) ? cn : kept;
  }
}

// ---------- np-exact recheck: 32 rows/block, line-perfect staging, cn==1 shortcut [r23] ----------
__global__ __launch_bounds__(256, 2) void vq_recheck(const float* __restrict__ x,
                                                     const float* __restrict__ cb,
                                                     const float* __restrict__ se,
                                                     const int* __restrict__ cnt,
                                                     const int* __restrict__ cand,
                                                     float* __restrict__ outids,
                                                     int* __restrict__ flg,
                                                     int* __restrict__ nflg) {
#pragma clang fp contract(off)
  __shared__ float xr[32 * XPAD];    // 33 KB
  __shared__ float sxs[32];
  const int t = threadIdx.x;
  const int rowbase = blockIdx.x * 32;
  const int b = rowbase >> 10, hw0 = rowbase & 1023;

  {
    const float* px = x + ((size_t)b * CD + t) * HW + hw0;
#pragma unroll
    for (int f = 0; f < 8; ++f) {
      const float4 v = *(const float4*)(px + 4 * f);
      xr[(4 * f + 0) * XPAD + t] = v.x;
      xr[(4 * f + 1) * XPAD + t] = v.y;
      xr[(4 * f + 2) * XPAD + t] = v.z;
      xr[(4 * f + 3) * XPAD + t] = v.w;
    }
  }
  __syncthreads();

  {
    const int g = t >> 3, j = t & 7;
    float half[2];
#pragma unroll
    for (int h = 0; h < 2; ++h) {
      const float* a = xr + g * XPAD + h * 128;
      float v = a[j];
      float r = v * v;
#pragma unroll
      for (int i = 1; i < 16; ++i) {
        float ww = a[8 * i + j];
        float w2 = ww * ww;
        r = r + w2;
      }
      float l1 = r + __shfl_down(r, 1, 8);
      float l2 = l1 + __shfl_down(l1, 2, 8);
      float l3 = l2 + __shfl_down(l2, 4, 8);
      half[h] = l3;
    }
    if (j == 0) sxs[g] = half[0] + half[1];
  }
  __syncthreads();

  {
    const int g = t >> 3, j = t & 7;
    const int row = rowbase + g;
    const int cn = cnt[row];
    if (cn > CAP) {
      if (j == 0) { const int p = atomicAdd(nflg, 1); flg[p] = row; }
    } else if (cn == 1) {
      if (j == 0) outids[row] = (float)cand[(size_t)row * CAP];
    } else {
      float bv = FLT_MAX;
      int bi = 0x7FFFFFFF;
      const float sx = sxs[g];
      const float* xrow = xr + g * XPAD;
      for (int c = j; c < cn; c += 8) {
        const int k = cand[(size_t)row * CAP + c];
        const float* ek = cb + (size_t)k * CD;
        float a0 = 0.f, a1 = 0.f, a2 = 0.f, a3 = 0.f;
        for (int B = 0; B < 16; ++B)
          for (int jj = 3; jj >= 0; --jj) {
            const int c0 = 16 * B + 4 * jj;
            float p0 = xrow[c0 + 0] * ek[c0 + 0]; a0 = a0 + p0;
            float p1 = xrow[c0 + 1] * ek[c0 + 1]; a1 = a1 + p1;
            float p2 = xrow[c0 + 2] * ek[c0 + 2]; a2 = a2 + p2;
            float p3 = xrow[c0 + 3] * ek[c0 + 3]; a3 = a3 + p3;
          }
        const float dot = (a0 + a1) + (a2 + a3);
        const float dist = (se[k] + sx) - 2.0f * dot;
        if (dist < bv || (dist == bv && k < bi)) { bv = dist; bi = k; }
      }
#pragma unroll
      for (int off = 1; off < 8; off <<= 1) {
        const float ov = __shfl_xor(bv, off, 8);
        const int oi = __shfl_xor(bi, off, 8);
        if (ov < bv || (ov == bv && oi < bi)) { bv = ov; bi = oi; }
      }
      if (j == 0) outids[row] = (float)bi;
    }
  }
}

// ---------- full-row np-exact fallback for overflow rows [verified] ----------
__global__ __launch_bounds__(256) void vq_fallback(const float* __restrict__ x,
                                                   const float* __restrict__ cb,
                                                   const float* __restrict__ se,
                                                   const int* __restrict__ flg,
                                                   const int* __restrict__ nflg,
                                                   float* __restrict__ outids) {
#pragma clang fp contract(off)
  __shared__ float xr[256];
  __shared__ float sxv;
  __shared__ float rv[256];
  __shared__ int ri[256];
  const int t = threadIdx.x;
  const int nf = *nflg;
  for (int fi = blockIdx.x; fi < nf; fi += gridDim.x) {
    const int row = flg[fi];
    const int b = row >> 10, hw = row & 1023;
    __syncthreads();
    xr[t] = x[((size_t)b * CD + t) * HW + hw];
    __syncthreads();
    if (t == 0) {
      float half[2];
      for (int h = 0; h < 2; ++h) {
        float racc[8];
        for (int j = 0; j < 8; ++j) { const float v = xr[h * 128 + j]; racc[j] = v * v; }
        for (int i = 1; i < 16; ++i)
          for (int j = 0; j < 8; ++j) {
            const float v = xr[h * 128 + 8 * i + j];
            const float v2 = v * v;
            racc[j] = racc[j] + v2;
          }
        half[h] = ((racc[0] + racc[1]) + (racc[2] + racc[3])) +
                  ((racc[4] + racc[5]) + (racc[6] + racc[7]));
      }
      sxv = half[0] + half[1];
    }
    __syncthreads();
    float bv = FLT_MAX;
    int bi = 0x7FFFFFFF;
    for (int j = 0; j < 16; ++j) {
      const int k = j * 256 + t;
      const float* ek = cb + (size_t)k * CD;
      float a0 = 0.f, a1 = 0.f, a2 = 0.f, a3 = 0.f;
      for (int B = 0; B < 16; ++B)
        for (int jj = 3; jj >= 0; --jj) {
          const int c0 = 16 * B + 4 * jj;
          float p0 = xr[c0 + 0] * ek[c0 + 0]; a0 = a0 + p0;
          float p1 = xr[c0 + 1] * ek[c0 + 1]; a1 = a1 + p1;
          float p2 = xr[c0 + 2] * ek[c0 + 2]; a2 = a2 + p2;
          float p3 = xr[c0 + 3] * ek[c0 + 3]; a3 = a3 + p3;
        }
      const float dot = (a0 + a1) + (a2 + a3);
      const float dist = (se[k] + sxv) - 2.0f * dot;
      if (dist < bv || (dist == bv && k < bi)) { bv = dist; bi = k; }
    }
    rv[t] = bv; ri[t] = bi;
    __syncthreads();
    for (int off = 128; off > 0; off >>= 1) {
      if (t < off) {
        if (rv[t + off] < rv[t] || (rv[t + off] == rv[t] && ri[t + off] < ri[t])) {
          rv[t] = rv[t + off]; ri[t] = ri[t + off];
        }
      }
      __syncthreads();
    }
    if (t == 0) outids[row] = (float)ri[0];
  }
}

// ---------- emb gather [verified] ----------
__global__ __launch_bounds__(256) void vq_emb_out(const float* __restrict__ outids,
                                                  const float* __restrict__ cb,
                                                  float* __restrict__ out) {
  const int bx = blockIdx.x;
  const int b = bx >> 10;
  const int rem = bx & 1023;
  const int c = rem >> 2;
  const int q = rem & 3;
  const int hw = q * 256 + threadIdx.x;
  const int id = (int)outids[b * HW + hw];
  out[((size_t)(b * CD + c)) * HW + hw] = cb[(size_t)id * CD + c];
}

extern "C" void kernel_launch(void* const* d_in, const int* in_sizes, int n_in,
                              void* d_out, int out_size, void* d_ws, size_t ws_size,
                              hipStream_t stream) {
  const float* x  = (const float*)d_in[0];   // (32,256,32,32) f32
  const float* cb = (const float*)d_in[1];   // (4096,256) f32
  float* out = (float*)d_out;                // [0..32767]=ids, [32768..]=emb

  float* se = (float*)d_ws;                  // 16 KB

  // scratch inside the emb region (8,388,608 floats), overwritten last by gather
  float* sc = out + NRW;
  unsigned short* xh = (unsigned short*)sc;              // 16.8 MB
  unsigned short* eh = (unsigned short*)(sc + 4194304);  // 2.1 MB (pre-swizzled granules)
  int*   cnt  = (int*)(sc + 4751360);                    // 32,768
  int*   flg  = (int*)(sc + 4784128);                    // 32,768
  int*   nflg = (int*)(sc + 4816896);                    // 1
  int*   cand = (int*)(sc + 4816960);                    // 32768*64 ints

  vq_se<<<KC / 32, 256, 0, stream>>>(cb, se, nflg);
  vq_cvt_x<<<512, 256, 0, stream>>>(x, xh);
  vq_cvt_e<<<512, 256, 0, stream>>>(cb, eh);
  vq_gemm<<<NRW / 64, 256, 0, stream>>>(xh, eh, cnt, cand);
  vq_recheck<<<NRW / 32, 256, 0, stream>>>(x, cb, se, cnt, cand, out, flg, nflg);
  vq_fallback<<<512, 256, 0, stream>>>(x, cb, se, flg, nflg, out);
  vq_emb_out<<<32768, 256, 0, stream>>>(out, cb, out + NRW);
}